// Round 4
// baseline (605.942 us; speedup 1.0000x reference)
//
#include <hip/hip_runtime.h>
#include <stdint.h>

#define NN 50000
#define NE 500000
#define ET 128         // edges per tile (persistent edge kernel)
#define NT ((NE + ET - 1) / ET)
#define BLK 256

#define BARRIER() asm volatile("s_waitcnt lgkmcnt(0)\n\ts_barrier" ::: "memory")

typedef __attribute__((ext_vector_type(8))) short bf16x8;
typedef __attribute__((ext_vector_type(4))) float f32x4;

__device__ __forceinline__ float silu(float x) { return x / (1.0f + __expf(-x)); }
__device__ __forceinline__ unsigned short f2bf(float f) {   // RNE float->bf16
    union { float f; unsigned int u; } v; v.f = f;
    return (unsigned short)((v.u + 0x7fffu + ((v.u >> 16) & 1u)) >> 16);
}
__device__ __forceinline__ unsigned int pack2(float a, float b) {
    return (unsigned int)f2bf(a) | ((unsigned int)f2bf(b) << 16);
}

// ---------------- prep kernels ----------------
__global__ void prep_h(const float* __restrict__ h, unsigned short* __restrict__ hb) {
    int i = blockIdx.x * 256 + threadIdx.x;
    if (i < NN * 128 / 4) {
        float4 v = ((const float4*)h)[i];
        uint2 o; o.x = pack2(v.x, v.y); o.y = pack2(v.z, v.w);
        ((uint2*)hb)[i] = o;
    }
}

// Wt1[j][k]=We1[k][j] (k<256 natural); Wt2/Wt3: sigma-permuted k rows of We2/Wc1.
// sigma(col) = (col%16)*8 + col/16  => orig_k(ks) = (ks%8)*16 + ks/8
__global__ void prep_w(const float* __restrict__ We1, const float* __restrict__ We2,
                       const float* __restrict__ Wc1,
                       unsigned short* __restrict__ Wt1, unsigned short* __restrict__ Wt2,
                       unsigned short* __restrict__ Wt3) {
    int i = blockIdx.x * 256 + threadIdx.x;
    if (i < 32768) {
        int j = i >> 8, k = i & 255;
        Wt1[i] = f2bf(We1[k * 128 + j]);
    } else if (i < 49152) {
        int t = i - 32768; int j = t >> 7, ks = t & 127;
        int k0 = (ks & 7) * 16 + (ks >> 3);
        Wt2[t] = f2bf(We2[k0 * 128 + j]);
    } else if (i < 65536) {
        int t = i - 49152; int j = t >> 7, ks = t & 127;
        int k0 = (ks & 7) * 16 + (ks >> 3);
        Wt3[t] = f2bf(Wc1[k0 * 128 + j]);
    }
}

// ---------------- persistent edge kernel ----------------
__global__ __launch_bounds__(BLK, 1) void egcl_edge(
    const float* __restrict__ coord,
    const int* __restrict__ eidx,
    const unsigned short* __restrict__ hb,
    const unsigned short* __restrict__ Wt1,
    const unsigned short* __restrict__ Wt2,
    const unsigned short* __restrict__ Wt3,
    const float* __restrict__ We1,
    const float* __restrict__ be1, const float* __restrict__ be2,
    const float* __restrict__ bc1,
    const float* __restrict__ Wc2, const float* __restrict__ bc2,
    float* __restrict__ m_acc, float* __restrict__ c_acc)
{
    __shared__ __align__(16) unsigned short sWt1[128 * 264];  // 67584 B, We1^T padded
    __shared__ __align__(16) unsigned short sWt3[128 * 136];  // 34816 B, Wc1^T sigma padded
    __shared__ __align__(16) unsigned short sAb[128 * 136];   // 34816 B, t1 then m (sigma)
    __shared__ float sRad[ET];
    __shared__ float sDif[ET][3];
    __shared__ int   sR[ET];
    __shared__ float sBe1[128], sBe2[128], sBc1[128], sWlast[128], sWc2f[128];

    const int tid = threadIdx.x;
    const int wv = tid >> 6, lane = tid & 63, q = lane >> 4, l16 = lane & 15;

    // ---- one-time: biases + resident weights ----
    if (tid < 128) {
        sBe1[tid] = be1[tid]; sBe2[tid] = be2[tid]; sBc1[tid] = bc1[tid];
        sWlast[tid] = We1[256 * 128 + tid]; sWc2f[tid] = Wc2[tid];
    }
#pragma unroll
    for (int t = 0; t < 16; ++t) {          // Wt1: 4096 uint4 -> padded LDS
        int idx = tid + t * 256; int j = idx >> 5, g = idx & 31;
        *(uint4*)(sWt1 + j * 264 + g * 8) = ((const uint4*)Wt1)[idx];
    }
#pragma unroll
    for (int t = 0; t < 8; ++t) {           // Wt3: 2048 uint4 -> padded LDS
        int idx = tid + t * 256; int j = idx >> 4, g = idx & 15;
        *(uint4*)(sWt3 + j * 136 + g * 8) = ((const uint4*)Wt3)[idx];
    }
    bf16x8 w2[8][4];                        // We2 B-fragments hoisted to VGPRs
#pragma unroll
    for (int ct = 0; ct < 8; ++ct)
#pragma unroll
        for (int kc = 0; kc < 4; ++kc)
            w2[ct][kc] = *(const bf16x8*)(Wt2 + (size_t)(ct * 16 + l16) * 128 + kc * 32 + q * 8);
    const float bc2v = bc2[0];
    __syncthreads();

    for (int tt = blockIdx.x; tt < NT; tt += 256) {
        const int e0 = tt * ET;
        int nval = NE - e0; if (nval > ET) nval = ET;

        BARRIER();   // B0: prev tile's sAb/sDif/sR reads complete before overwrite

        if (tid < ET) {     // geometry + row indices for this tile
            int e = e0 + tid; if (e >= NE) e = NE - 1;
            int r = eidx[e], c = eidx[NE + e];
            sR[tid] = r;
            float dx = coord[r * 3 + 0] - coord[c * 3 + 0];
            float dy = coord[r * 3 + 1] - coord[c * 3 + 1];
            float dz = coord[r * 3 + 2] - coord[c * 3 + 2];
            float rad = fmaf(dx, dx, fmaf(dy, dy, dz * dz));
            float inv = 1.0f / (sqrtf(rad) + 1e-8f);
            sRad[tid] = rad;
            sDif[tid][0] = dx * inv; sDif[tid][1] = dy * inv; sDif[tid][2] = dz * inv;
        }

        // ---- e1: A direct from global, B from resident sWt1 ----
        bf16x8 a1[2][8];
#pragma unroll
        for (int si = 0; si < 2; ++si) {
            int row = (wv * 2 + si) * 16 + l16;
            int e = e0 + row; if (e >= NE) e = NE - 1;
            int rr = eidx[e], cc = eidx[NE + e];
#pragma unroll
            for (int kc = 0; kc < 8; ++kc) {
                int node = (kc < 4) ? rr : cc;
                a1[si][kc] = *(const bf16x8*)(hb + (size_t)node * 128 + (kc & 3) * 32 + q * 8);
            }
        }
        f32x4 acc1[2][8];
#pragma unroll
        for (int si = 0; si < 2; ++si)
#pragma unroll
            for (int ct = 0; ct < 8; ++ct) acc1[si][ct] = (f32x4){0.f, 0.f, 0.f, 0.f};
#pragma unroll
        for (int kc = 0; kc < 8; ++kc)
#pragma unroll
            for (int ct = 0; ct < 8; ++ct) {
                bf16x8 b = *(const bf16x8*)(sWt1 + (ct * 16 + l16) * 264 + kc * 32 + q * 8);
                acc1[0][ct] = __builtin_amdgcn_mfma_f32_16x16x32_bf16(a1[0][kc], b, acc1[0][ct], 0, 0, 0);
                acc1[1][ct] = __builtin_amdgcn_mfma_f32_16x16x32_bf16(a1[1][kc], b, acc1[1][ct], 0, 0, 0);
            }

        BARRIER();   // B1: geometry visible; sAb free for t1 writes

        // e1 epilogue: silu(acc + rad*Wlast + be1) -> sigma-packed t1 in sAb
#pragma unroll
        for (int si = 0; si < 2; ++si)
#pragma unroll
            for (int r = 0; r < 4; ++r) {
                int row = (wv * 2 + si) * 16 + q * 4 + r;
                float rad = sRad[row];
                float v[8];
#pragma unroll
                for (int ct = 0; ct < 8; ++ct) {
                    int col = ct * 16 + l16;
                    v[ct] = silu(acc1[si][ct][r] + rad * sWlast[col] + sBe1[col]);
                }
                uint4 pk = make_uint4(pack2(v[0], v[1]), pack2(v[2], v[3]),
                                      pack2(v[4], v[5]), pack2(v[6], v[7]));
                *(uint4*)(sAb + row * 136 + l16 * 8) = pk;
            }

        BARRIER();   // B2: t1 visible

        // ---- e2: A from sAb, B from VGPR-hoisted w2 ----
        f32x4 acc2[2][8];
#pragma unroll
        for (int si = 0; si < 2; ++si)
#pragma unroll
            for (int ct = 0; ct < 8; ++ct) acc2[si][ct] = (f32x4){0.f, 0.f, 0.f, 0.f};
        {
            bf16x8 a2[2][4];
#pragma unroll
            for (int si = 0; si < 2; ++si) {
                int row = (wv * 2 + si) * 16 + l16;
#pragma unroll
                for (int kc = 0; kc < 4; ++kc)
                    a2[si][kc] = *(const bf16x8*)(sAb + row * 136 + kc * 32 + q * 8);
            }
#pragma unroll
            for (int kc = 0; kc < 4; ++kc)
#pragma unroll
                for (int ct = 0; ct < 8; ++ct) {
                    acc2[0][ct] = __builtin_amdgcn_mfma_f32_16x16x32_bf16(a2[0][kc], w2[ct][kc], acc2[0][ct], 0, 0, 0);
                    acc2[1][ct] = __builtin_amdgcn_mfma_f32_16x16x32_bf16(a2[1][kc], w2[ct][kc], acc2[1][ct], 0, 0, 0);
                }
        }
        // e2 epilogue: m -> atomics (global, no barrier interaction) + packed regs
        uint4 mu[2][4];
#pragma unroll
        for (int si = 0; si < 2; ++si)
#pragma unroll
            for (int r = 0; r < 4; ++r) {
                int row = (wv * 2 + si) * 16 + q * 4 + r;
                float v[8];
#pragma unroll
                for (int ct = 0; ct < 8; ++ct) v[ct] = silu(acc2[si][ct][r] + sBe2[ct * 16 + l16]);
                mu[si][r] = make_uint4(pack2(v[0], v[1]), pack2(v[2], v[3]),
                                       pack2(v[4], v[5]), pack2(v[6], v[7]));
                if (row < nval) {
                    float* mrow = m_acc + (size_t)sR[row] * 128;
#pragma unroll
                    for (int ct = 0; ct < 8; ++ct) atomicAdd(mrow + ct * 16 + l16, v[ct]);
                }
            }

        BARRIER();   // B3: all e2 A-reads of sAb done before m overwrites it
#pragma unroll
        for (int si = 0; si < 2; ++si)
#pragma unroll
            for (int r = 0; r < 4; ++r) {
                int row = (wv * 2 + si) * 16 + q * 4 + r;
                *(uint4*)(sAb + row * 136 + l16 * 8) = mu[si][r];
            }
        BARRIER();   // B4: m visible

        // ---- c1: A from sAb, B from resident sWt3 ----
        f32x4 acc3[2][8];
#pragma unroll
        for (int si = 0; si < 2; ++si)
#pragma unroll
            for (int ct = 0; ct < 8; ++ct) acc3[si][ct] = (f32x4){0.f, 0.f, 0.f, 0.f};
        {
            bf16x8 a3[2][4];
#pragma unroll
            for (int si = 0; si < 2; ++si) {
                int row = (wv * 2 + si) * 16 + l16;
#pragma unroll
                for (int kc = 0; kc < 4; ++kc)
                    a3[si][kc] = *(const bf16x8*)(sAb + row * 136 + kc * 32 + q * 8);
            }
#pragma unroll
            for (int kc = 0; kc < 4; ++kc)
#pragma unroll
                for (int ct = 0; ct < 8; ++ct) {
                    bf16x8 b = *(const bf16x8*)(sWt3 + (ct * 16 + l16) * 136 + kc * 32 + q * 8);
                    acc3[0][ct] = __builtin_amdgcn_mfma_f32_16x16x32_bf16(a3[0][kc], b, acc3[0][ct], 0, 0, 0);
                    acc3[1][ct] = __builtin_amdgcn_mfma_f32_16x16x32_bf16(a3[1][kc], b, acc3[1][ct], 0, 0, 0);
                }
        }
        // c2: silu -> dot Wc2 -> 16-lane reduce -> coord atomics
#pragma unroll
        for (int si = 0; si < 2; ++si) {
            float p[4];
#pragma unroll
            for (int r = 0; r < 4; ++r) {
                float s = 0.f;
#pragma unroll
                for (int ct = 0; ct < 8; ++ct) {
                    int col = ct * 16 + l16;
                    float t = silu(acc3[si][ct][r] + sBc1[col]);
                    s = fmaf(t, sWc2f[col], s);
                }
                p[r] = s;
            }
#pragma unroll
            for (int m = 1; m < 16; m <<= 1)
#pragma unroll
                for (int r = 0; r < 4; ++r) p[r] += __shfl_xor(p[r], m, 16);
            if (l16 == 0) {
#pragma unroll
                for (int r = 0; r < 4; ++r) {
                    int row = (wv * 2 + si) * 16 + q * 4 + r;
                    if (row < nval) {
                        int rn = sR[row]; float w = p[r] + bc2v;
                        atomicAdd(&c_acc[(size_t)rn * 3 + 0], sDif[row][0] * w);
                        atomicAdd(&c_acc[(size_t)rn * 3 + 1], sDif[row][1] * w);
                        atomicAdd(&c_acc[(size_t)rn * 3 + 2], sDif[row][2] * w);
                    }
                }
            }
        }
    }
}

// ---------------- node kernel (unchanged fp32 path) ----------------
template <int K>
__device__ __forceinline__ void gemm_tile(
    float (&sA)[32][264], float (&sW)[32][128],
    const float* __restrict__ W, int acol,
    int tid, int trow, int tcol, float (&acc)[4][4])
{
    const float4* W4 = reinterpret_cast<const float4*>(W);
    for (int k0 = 0; k0 < K; k0 += 32) {
        __syncthreads();
#pragma unroll
        for (int t = 0; t < 4; ++t) {
            int idx = tid + t * BLK;
            int kk = idx >> 5, c4 = idx & 31;
            *reinterpret_cast<float4*>(&sW[kk][c4 * 4]) = W4[(size_t)(k0 + kk) * 32 + c4];
        }
        __syncthreads();
#pragma unroll
        for (int kq = 0; kq < 8; ++kq) {
            const float4 b0 = *reinterpret_cast<const float4*>(&sW[4 * kq + 0][tcol * 4]);
            const float4 b1 = *reinterpret_cast<const float4*>(&sW[4 * kq + 1][tcol * 4]);
            const float4 b2 = *reinterpret_cast<const float4*>(&sW[4 * kq + 2][tcol * 4]);
            const float4 b3 = *reinterpret_cast<const float4*>(&sW[4 * kq + 3][tcol * 4]);
#pragma unroll
            for (int i = 0; i < 4; ++i) {
                const float4 a = *reinterpret_cast<const float4*>(&sA[trow * 4 + i][acol + k0 + 4 * kq]);
                acc[i][0] = fmaf(a.x, b0.x, fmaf(a.y, b1.x, fmaf(a.z, b2.x, fmaf(a.w, b3.x, acc[i][0]))));
                acc[i][1] = fmaf(a.x, b0.y, fmaf(a.y, b1.y, fmaf(a.z, b2.y, fmaf(a.w, b3.y, acc[i][1]))));
                acc[i][2] = fmaf(a.x, b0.z, fmaf(a.y, b1.z, fmaf(a.z, b2.z, fmaf(a.w, b3.z, acc[i][2]))));
                acc[i][3] = fmaf(a.x, b0.w, fmaf(a.y, b1.w, fmaf(a.z, b2.w, fmaf(a.w, b3.w, acc[i][3]))));
            }
        }
    }
}

__global__ __launch_bounds__(BLK) void egcl_node(
    const float* __restrict__ h,
    const float* __restrict__ coord,
    const float* __restrict__ vel,
    const float* __restrict__ Wv1, const float* __restrict__ bv1,
    const float* __restrict__ Wv2, const float* __restrict__ bv2,
    const float* __restrict__ Wn1, const float* __restrict__ bn1,
    const float* __restrict__ Wn2, const float* __restrict__ bn2,
    const float* __restrict__ m_acc, const float* __restrict__ c_acc,
    float* __restrict__ out_h, float* __restrict__ out_c)
{
    __shared__ float sA[32][264];
    __shared__ float sW[32][128];
    __shared__ float sWv2[128];

    const int tid  = threadIdx.x;
    const int trow = tid >> 5, tcol = tid & 31;
    const int n0   = blockIdx.x * 32;

    if (tid < 128) sWv2[tid] = Wv2[tid];

    {
        int e = tid >> 3, l8 = tid & 7;
        int n = n0 + e; int nn = (n < NN) ? n : (NN - 1);
        const float4* ph = reinterpret_cast<const float4*>(h + (size_t)nn * 128) + l8 * 4;
        const float4* pm = reinterpret_cast<const float4*>(m_acc + (size_t)nn * 128) + l8 * 4;
#pragma unroll
        for (int qq = 0; qq < 4; ++qq) {
            *reinterpret_cast<float4*>(&sA[e][l8 * 16 + qq * 4])       = ph[qq];
            *reinterpret_cast<float4*>(&sA[e][128 + l8 * 16 + qq * 4]) = pm[qq];
        }
    }

    float acc[4][4];
#pragma unroll
    for (int i = 0; i < 4; ++i) { acc[i][0] = acc[i][1] = acc[i][2] = acc[i][3] = 0.f; }
    gemm_tile<128>(sA, sW, Wv1, 0, tid, trow, tcol, acc);
    float p[4] = {0.f, 0.f, 0.f, 0.f};
#pragma unroll
    for (int i = 0; i < 4; ++i)
#pragma unroll
        for (int jj = 0; jj < 4; ++jj) {
            int j = tcol * 4 + jj;
            float t = silu(acc[i][jj] + bv1[j]);
            p[i] = fmaf(t, sWv2[j], p[i]);
        }
#pragma unroll
    for (int off = 16; off > 0; off >>= 1) {
#pragma unroll
        for (int i = 0; i < 4; ++i) p[i] += __shfl_down(p[i], off, 32);
    }
    if (tcol == 0) {
        float bv2v = bv2[0];
#pragma unroll
        for (int i = 0; i < 4; ++i) {
            int e = trow * 4 + i; int n = n0 + e;
            if (n < NN) {
                float vw = p[i] + bv2v;
#pragma unroll
                for (int d = 0; d < 3; ++d) {
                    float cv = coord[(size_t)n * 3 + d] + c_acc[(size_t)n * 3 + d]
                             + vel[(size_t)n * 3 + d] * vw;
                    out_c[(size_t)n * 3 + d] = cv;
                }
            }
        }
    }

#pragma unroll
    for (int i = 0; i < 4; ++i) { acc[i][0] = acc[i][1] = acc[i][2] = acc[i][3] = 0.f; }
    gemm_tile<256>(sA, sW, Wn1, 0, tid, trow, tcol, acc);
    float t1v[4][4];
#pragma unroll
    for (int i = 0; i < 4; ++i)
#pragma unroll
        for (int jj = 0; jj < 4; ++jj)
            t1v[i][jj] = silu(acc[i][jj] + bn1[tcol * 4 + jj]);
    __syncthreads();
#pragma unroll
    for (int i = 0; i < 4; ++i)
        *reinterpret_cast<float4*>(&sA[trow * 4 + i][132 + tcol * 4]) =
            make_float4(t1v[i][0], t1v[i][1], t1v[i][2], t1v[i][3]);

#pragma unroll
    for (int i = 0; i < 4; ++i) { acc[i][0] = acc[i][1] = acc[i][2] = acc[i][3] = 0.f; }
    gemm_tile<128>(sA, sW, Wn2, 132, tid, trow, tcol, acc);
#pragma unroll
    for (int i = 0; i < 4; ++i) {
        int e = trow * 4 + i; int n = n0 + e;
        if (n < NN) {
            float4 pk;
            pk.x = acc[i][0] + bn2[tcol * 4 + 0];
            pk.y = acc[i][1] + bn2[tcol * 4 + 1];
            pk.z = acc[i][2] + bn2[tcol * 4 + 2];
            pk.w = acc[i][3] + bn2[tcol * 4 + 3];
            *reinterpret_cast<float4*>(out_h + (size_t)n * 128 + tcol * 4) = pk;
        }
    }
}

extern "C" void kernel_launch(void* const* d_in, const int* in_sizes, int n_in,
                              void* d_out, int out_size, void* d_ws, size_t ws_size,
                              hipStream_t stream) {
    const float* h     = (const float*)d_in[0];
    const float* coord = (const float*)d_in[1];
    const float* vel   = (const float*)d_in[2];
    const int*   eidx  = (const int*)d_in[3];
    const float* We1 = (const float*)d_in[4];
    const float* be1 = (const float*)d_in[5];
    const float* We2 = (const float*)d_in[6];
    const float* be2 = (const float*)d_in[7];
    const float* Wc1 = (const float*)d_in[8];
    const float* bc1 = (const float*)d_in[9];
    const float* Wc2 = (const float*)d_in[10];
    const float* bc2 = (const float*)d_in[11];
    const float* Wv1 = (const float*)d_in[12];
    const float* bv1 = (const float*)d_in[13];
    const float* Wv2 = (const float*)d_in[14];
    const float* bv2 = (const float*)d_in[15];
    const float* Wn1 = (const float*)d_in[16];
    const float* bn1 = (const float*)d_in[17];
    const float* Wn2 = (const float*)d_in[18];
    const float* bn2 = (const float*)d_in[19];

    char* ws = (char*)d_ws;
    float* m_acc = (float*)ws;                                 // [NN,128] f32 = 25.6 MB
    float* c_acc = (float*)(ws + 25600000);                    // [NN,3]  f32
    unsigned short* hb  = (unsigned short*)(ws + 26200064);    // [NN,128] bf16
    unsigned short* Wt1 = (unsigned short*)(ws + 39000064);    // [128][256] bf16
    unsigned short* Wt2 = (unsigned short*)(ws + 39065600);    // [128][128] bf16 (sigma-k)
    unsigned short* Wt3 = (unsigned short*)(ws + 39098368);    // [128][128] bf16 (sigma-k)

    hipMemsetAsync(d_ws, 0, 26200000, stream);
    prep_h<<<6250, 256, 0, stream>>>(h, hb);
    prep_w<<<256, 256, 0, stream>>>(We1, We2, Wc1, Wt1, Wt2, Wt3);

    egcl_edge<<<256, BLK, 0, stream>>>(
        coord, eidx, hb, Wt1, Wt2, Wt3,
        We1, be1, be2, bc1, Wc2, bc2, m_acc, c_acc);

    float* out_h = (float*)d_out;
    float* out_c = out_h + (size_t)NN * 128;
    egcl_node<<<(NN + 31) / 32, BLK, 0, stream>>>(h, coord, vel,
                                                  Wv1, bv1, Wv2, bv2,
                                                  Wn1, bn1, Wn2, bn2,
                                                  m_acc, c_acc, out_h, out_c);
}

// Round 5
// 585.437 us; speedup vs baseline: 1.0350x; 1.0350x over previous
//
#include <hip/hip_runtime.h>
#include <stdint.h>

#define NN 50000
#define NE 500000
#define BLK 256
#define SAB_STRIDE 140   // shorts; 280B row stride -> ~2-way LDS banks

#define BARRIER() asm volatile("s_waitcnt lgkmcnt(0)\n\ts_barrier" ::: "memory")

typedef __attribute__((ext_vector_type(8))) short bf16x8;
typedef __attribute__((ext_vector_type(4))) float f32x4;

__device__ __forceinline__ float silu(float x) { return x / (1.0f + __expf(-x)); }
__device__ __forceinline__ unsigned short f2bf(float f) {   // RNE float->bf16
    union { float f; unsigned int u; } v; v.f = f;
    return (unsigned short)((v.u + 0x7fffu + ((v.u >> 16) & 1u)) >> 16);
}
__device__ __forceinline__ unsigned int pack2(float a, float b) {
    return (unsigned int)f2bf(a) | ((unsigned int)f2bf(b) << 16);
}
__device__ __forceinline__ bf16x8 packf8(const float* p) {   // 8 fp32 -> bf16x8
    float4 f0 = *(const float4*)p; float4 f1 = *(const float4*)(p + 4);
    union { bf16x8 v; unsigned int u[4]; } o;
    o.u[0] = pack2(f0.x, f0.y); o.u[1] = pack2(f0.z, f0.w);
    o.u[2] = pack2(f1.x, f1.y); o.u[3] = pack2(f1.z, f1.w);
    return o.v;
}

// ---------------- prep kernels ----------------
__global__ void prep_h(const float* __restrict__ h, unsigned short* __restrict__ hb) {
    int i = blockIdx.x * 256 + threadIdx.x;
    if (i < NN * 128 / 4) {
        float4 v = ((const float4*)h)[i];
        uint2 o; o.x = pack2(v.x, v.y); o.y = pack2(v.z, v.w);
        ((uint2*)hb)[i] = o;
    }
}

// B^T layouts. natural k: Wt[j][k] = W[k][j].
// sigma k: Wt[j][ks] = W[orig_k(ks)][j], orig_k(ks) = (ks%8)*16 + ks/8
__global__ void prep_w(const float* __restrict__ We1, const float* __restrict__ We2,
                       const float* __restrict__ Wc1, const float* __restrict__ Wv1,
                       const float* __restrict__ Wn1, const float* __restrict__ Wn2,
                       unsigned short* __restrict__ Wt1, unsigned short* __restrict__ Wt2,
                       unsigned short* __restrict__ Wt3, unsigned short* __restrict__ Wv1t,
                       unsigned short* __restrict__ Wn1t, unsigned short* __restrict__ Wn2t) {
    int i = blockIdx.x * 256 + threadIdx.x;
    if (i < 32768) {                                    // Wt1 [128][256] natural
        int j = i >> 8, k = i & 255;
        Wt1[i] = f2bf(We1[k * 128 + j]);
    } else if (i < 49152) {                             // Wt2 [128][128] sigma
        int t = i - 32768; int j = t >> 7, ks = t & 127;
        int k0 = (ks & 7) * 16 + (ks >> 3);
        Wt2[t] = f2bf(We2[k0 * 128 + j]);
    } else if (i < 65536) {                             // Wt3 [128][128] sigma
        int t = i - 49152; int j = t >> 7, ks = t & 127;
        int k0 = (ks & 7) * 16 + (ks >> 3);
        Wt3[t] = f2bf(Wc1[k0 * 128 + j]);
    } else if (i < 81920) {                             // Wv1t [128][128] natural
        int t = i - 65536; int j = t >> 7, k = t & 127;
        Wv1t[t] = f2bf(Wv1[k * 128 + j]);
    } else if (i < 114688) {                            // Wn1t [128][256] natural
        int t = i - 81920; int j = t >> 8, k = t & 255;
        Wn1t[t] = f2bf(Wn1[k * 128 + j]);
    } else if (i < 131072) {                            // Wn2t [128][128] sigma
        int t = i - 114688; int j = t >> 7, ks = t & 127;
        int k0 = (ks & 7) * 16 + (ks >> 3);
        Wn2t[t] = f2bf(Wn2[k0 * 128 + j]);
    }
}

// ---------------- edge kernel: one 128-edge tile per block ----------------
__global__ __launch_bounds__(BLK, 3) void egcl_edge(
    const float* __restrict__ coord,
    const int* __restrict__ eidx,
    const unsigned short* __restrict__ hb,
    const unsigned short* __restrict__ Wt1,
    const unsigned short* __restrict__ Wt2,
    const unsigned short* __restrict__ Wt3,
    const float* __restrict__ We1,
    const float* __restrict__ be1, const float* __restrict__ be2,
    const float* __restrict__ bc1,
    const float* __restrict__ Wc2, const float* __restrict__ bc2,
    float* __restrict__ m_acc, float* __restrict__ c_acc)
{
    __shared__ __align__(16) unsigned short sAb[128 * SAB_STRIDE];
    __shared__ float sRad[128];
    __shared__ float sDif[128][3];
    __shared__ int   sR[128];
    __shared__ float sBe1[128], sBe2[128], sBc1[128], sWlast[128], sWc2f[128];

    const int tid = threadIdx.x;
    const int wv = tid >> 6, lane = tid & 63, q = lane >> 4, l16 = lane & 15;
    const int e0 = blockIdx.x * 128;
    int nval = NE - e0; if (nval > 128) nval = 128;

    if (tid < 128) {
        sBe1[tid] = be1[tid]; sBe2[tid] = be2[tid]; sBc1[tid] = bc1[tid];
        sWlast[tid] = We1[256 * 128 + tid]; sWc2f[tid] = Wc2[tid];
        // geometry
        int e = e0 + tid; if (e >= NE) e = NE - 1;
        int r = eidx[e], c = eidx[NE + e];
        sR[tid] = r;
        float dx = coord[r * 3 + 0] - coord[c * 3 + 0];
        float dy = coord[r * 3 + 1] - coord[c * 3 + 1];
        float dz = coord[r * 3 + 2] - coord[c * 3 + 2];
        float rad = fmaf(dx, dx, fmaf(dy, dy, dz * dz));
        float inv = 1.0f / (sqrtf(rad) + 1e-8f);
        sRad[tid] = rad;
        sDif[tid][0] = dx * inv; sDif[tid][1] = dy * inv; sDif[tid][2] = dz * inv;
    }
    const float bc2v = bc2[0];

    // ---- e1: A from global hb (2 halves: r-node then c-node), B from global Wt1
    f32x4 acc[2][8];
#pragma unroll
    for (int si = 0; si < 2; ++si)
#pragma unroll
        for (int ct = 0; ct < 8; ++ct) acc[si][ct] = (f32x4){0.f, 0.f, 0.f, 0.f};

#pragma unroll
    for (int half = 0; half < 2; ++half) {
        bf16x8 a[2][4];
#pragma unroll
        for (int si = 0; si < 2; ++si) {
            int row = (wv * 2 + si) * 16 + l16;
            int e = e0 + row; if (e >= NE) e = NE - 1;
            int node = (half == 0) ? eidx[e] : eidx[NE + e];
#pragma unroll
            for (int kc = 0; kc < 4; ++kc)
                a[si][kc] = *(const bf16x8*)(hb + (size_t)node * 128 + kc * 32 + q * 8);
        }
#pragma unroll
        for (int kc = 0; kc < 4; ++kc)
#pragma unroll
            for (int ct = 0; ct < 8; ++ct) {
                bf16x8 b = *(const bf16x8*)(Wt1 + (size_t)(ct * 16 + l16) * 256 + (half * 4 + kc) * 32 + q * 8);
                acc[0][ct] = __builtin_amdgcn_mfma_f32_16x16x32_bf16(a[0][kc], b, acc[0][ct], 0, 0, 0);
                acc[1][ct] = __builtin_amdgcn_mfma_f32_16x16x32_bf16(a[1][kc], b, acc[1][ct], 0, 0, 0);
            }
    }

    BARRIER();   // B1: geometry + biases visible

    // e1 epilogue: t1 = silu(acc + rad*Wlast + be1), sigma-packed into sAb
#pragma unroll
    for (int si = 0; si < 2; ++si)
#pragma unroll
        for (int r = 0; r < 4; ++r) {
            int row = (wv * 2 + si) * 16 + q * 4 + r;
            float rad = sRad[row];
            float v[8];
#pragma unroll
            for (int ct = 0; ct < 8; ++ct) {
                int col = ct * 16 + l16;
                v[ct] = silu(acc[si][ct][r] + rad * sWlast[col] + sBe1[col]);
            }
            uint4 pk = make_uint4(pack2(v[0], v[1]), pack2(v[2], v[3]),
                                  pack2(v[4], v[5]), pack2(v[6], v[7]));
            *(uint4*)(sAb + row * SAB_STRIDE + l16 * 8) = pk;
        }

    BARRIER();   // B2: t1 visible

    // ---- e2: A from sAb, B from global Wt2 (sigma)
#pragma unroll
    for (int si = 0; si < 2; ++si)
#pragma unroll
        for (int ct = 0; ct < 8; ++ct) acc[si][ct] = (f32x4){0.f, 0.f, 0.f, 0.f};
    {
        bf16x8 a[2][4];
#pragma unroll
        for (int si = 0; si < 2; ++si) {
            int row = (wv * 2 + si) * 16 + l16;
#pragma unroll
            for (int kc = 0; kc < 4; ++kc)
                a[si][kc] = *(const bf16x8*)(sAb + row * SAB_STRIDE + kc * 32 + q * 8);
        }
#pragma unroll
        for (int kc = 0; kc < 4; ++kc)
#pragma unroll
            for (int ct = 0; ct < 8; ++ct) {
                bf16x8 b = *(const bf16x8*)(Wt2 + (size_t)(ct * 16 + l16) * 128 + kc * 32 + q * 8);
                acc[0][ct] = __builtin_amdgcn_mfma_f32_16x16x32_bf16(a[0][kc], b, acc[0][ct], 0, 0, 0);
                acc[1][ct] = __builtin_amdgcn_mfma_f32_16x16x32_bf16(a[1][kc], b, acc[1][ct], 0, 0, 0);
            }
    }
    // e2 epilogue: m -> fp32 atomics + packed regs for LDS handoff
    uint4 mu[2][4];
#pragma unroll
    for (int si = 0; si < 2; ++si)
#pragma unroll
        for (int r = 0; r < 4; ++r) {
            int row = (wv * 2 + si) * 16 + q * 4 + r;
            float v[8];
#pragma unroll
            for (int ct = 0; ct < 8; ++ct) v[ct] = silu(acc[si][ct][r] + sBe2[ct * 16 + l16]);
            mu[si][r] = make_uint4(pack2(v[0], v[1]), pack2(v[2], v[3]),
                                   pack2(v[4], v[5]), pack2(v[6], v[7]));
            if (row < nval) {
                float* mrow = m_acc + (size_t)sR[row] * 128;
#pragma unroll
                for (int ct = 0; ct < 8; ++ct) atomicAdd(mrow + ct * 16 + l16, v[ct]);
            }
        }

    BARRIER();   // B3: all e2 A-reads of sAb done
#pragma unroll
    for (int si = 0; si < 2; ++si)
#pragma unroll
        for (int r = 0; r < 4; ++r) {
            int row = (wv * 2 + si) * 16 + q * 4 + r;
            *(uint4*)(sAb + row * SAB_STRIDE + l16 * 8) = mu[si][r];
        }
    BARRIER();   // B4: m visible

    // ---- c1: A from sAb, B from global Wt3 (sigma)
#pragma unroll
    for (int si = 0; si < 2; ++si)
#pragma unroll
        for (int ct = 0; ct < 8; ++ct) acc[si][ct] = (f32x4){0.f, 0.f, 0.f, 0.f};
    {
        bf16x8 a[2][4];
#pragma unroll
        for (int si = 0; si < 2; ++si) {
            int row = (wv * 2 + si) * 16 + l16;
#pragma unroll
            for (int kc = 0; kc < 4; ++kc)
                a[si][kc] = *(const bf16x8*)(sAb + row * SAB_STRIDE + kc * 32 + q * 8);
        }
#pragma unroll
        for (int kc = 0; kc < 4; ++kc)
#pragma unroll
            for (int ct = 0; ct < 8; ++ct) {
                bf16x8 b = *(const bf16x8*)(Wt3 + (size_t)(ct * 16 + l16) * 128 + kc * 32 + q * 8);
                acc[0][ct] = __builtin_amdgcn_mfma_f32_16x16x32_bf16(a[0][kc], b, acc[0][ct], 0, 0, 0);
                acc[1][ct] = __builtin_amdgcn_mfma_f32_16x16x32_bf16(a[1][kc], b, acc[1][ct], 0, 0, 0);
            }
    }
    // c2: silu -> dot Wc2 -> 16-lane reduce -> coord atomics
#pragma unroll
    for (int si = 0; si < 2; ++si) {
        float p[4];
#pragma unroll
        for (int r = 0; r < 4; ++r) {
            float s = 0.f;
#pragma unroll
            for (int ct = 0; ct < 8; ++ct) {
                int col = ct * 16 + l16;
                float t = silu(acc[si][ct][r] + sBc1[col]);
                s = fmaf(t, sWc2f[col], s);
            }
            p[r] = s;
        }
#pragma unroll
        for (int m = 1; m < 16; m <<= 1)
#pragma unroll
            for (int r = 0; r < 4; ++r) p[r] += __shfl_xor(p[r], m, 16);
        if (l16 == 0) {
#pragma unroll
            for (int r = 0; r < 4; ++r) {
                int row = (wv * 2 + si) * 16 + q * 4 + r;
                if (row < nval) {
                    int rn = sR[row]; float w = p[r] + bc2v;
                    atomicAdd(&c_acc[(size_t)rn * 3 + 0], sDif[row][0] * w);
                    atomicAdd(&c_acc[(size_t)rn * 3 + 1], sDif[row][1] * w);
                    atomicAdd(&c_acc[(size_t)rn * 3 + 2], sDif[row][2] * w);
                }
            }
        }
    }
}

// ---------------- node kernel: MFMA vel-MLP + node-MLP, 128 nodes/block ----------------
__global__ __launch_bounds__(BLK, 3) void egcl_node(
    const unsigned short* __restrict__ hb,
    const float* __restrict__ coord,
    const float* __restrict__ vel,
    const unsigned short* __restrict__ Wv1t, const float* __restrict__ bv1,
    const float* __restrict__ Wv2, const float* __restrict__ bv2,
    const unsigned short* __restrict__ Wn1t, const float* __restrict__ bn1,
    const unsigned short* __restrict__ Wn2t, const float* __restrict__ bn2,
    const float* __restrict__ m_acc, const float* __restrict__ c_acc,
    float* __restrict__ out_h, float* __restrict__ out_c)
{
    __shared__ __align__(16) unsigned short sAb[128 * SAB_STRIDE];
    __shared__ float sBv1[128], sWv2f[128], sBn1[128], sBn2[128];

    const int tid = threadIdx.x;
    const int wv = tid >> 6, lane = tid & 63, q = lane >> 4, l16 = lane & 15;
    const int n0 = blockIdx.x * 128;
    int nval = NN - n0; if (nval > 128) nval = 128;

    if (tid < 128) {
        sBv1[tid] = bv1[tid]; sWv2f[tid] = Wv2[tid];
        sBn1[tid] = bn1[tid]; sBn2[tid] = bn2[tid];
    }
    const float bv2v = bv2[0];

    // A fragments: h part (k 0..127) from hb; m part (k 128..255) from m_acc fp32
    bf16x8 ah[2][4], am[2][4];
#pragma unroll
    for (int si = 0; si < 2; ++si) {
        int row = (wv * 2 + si) * 16 + l16;
        int nn = n0 + row; if (nn >= NN) nn = NN - 1;
#pragma unroll
        for (int kc = 0; kc < 4; ++kc) {
            ah[si][kc] = *(const bf16x8*)(hb + (size_t)nn * 128 + kc * 32 + q * 8);
            am[si][kc] = packf8(m_acc + (size_t)nn * 128 + kc * 32 + q * 8);
        }
    }

    BARRIER();   // biases visible

    f32x4 acc[2][8];
    // ---- vel MLP: K=128 on h
#pragma unroll
    for (int si = 0; si < 2; ++si)
#pragma unroll
        for (int ct = 0; ct < 8; ++ct) acc[si][ct] = (f32x4){0.f, 0.f, 0.f, 0.f};
#pragma unroll
    for (int kc = 0; kc < 4; ++kc)
#pragma unroll
        for (int ct = 0; ct < 8; ++ct) {
            bf16x8 b = *(const bf16x8*)(Wv1t + (size_t)(ct * 16 + l16) * 128 + kc * 32 + q * 8);
            acc[0][ct] = __builtin_amdgcn_mfma_f32_16x16x32_bf16(ah[0][kc], b, acc[0][ct], 0, 0, 0);
            acc[1][ct] = __builtin_amdgcn_mfma_f32_16x16x32_bf16(ah[1][kc], b, acc[1][ct], 0, 0, 0);
        }
#pragma unroll
    for (int si = 0; si < 2; ++si) {
        float p[4];
#pragma unroll
        for (int r = 0; r < 4; ++r) {
            float s = 0.f;
#pragma unroll
            for (int ct = 0; ct < 8; ++ct) {
                int col = ct * 16 + l16;
                float t = silu(acc[si][ct][r] + sBv1[col]);
                s = fmaf(t, sWv2f[col], s);
            }
            p[r] = s;
        }
#pragma unroll
        for (int m = 1; m < 16; m <<= 1)
#pragma unroll
            for (int r = 0; r < 4; ++r) p[r] += __shfl_xor(p[r], m, 16);
        if (l16 == 0) {
#pragma unroll
            for (int r = 0; r < 4; ++r) {
                int row = (wv * 2 + si) * 16 + q * 4 + r;
                int n = n0 + row;
                if (row < nval) {
                    float vw = p[r] + bv2v;
#pragma unroll
                    for (int d = 0; d < 3; ++d) {
                        float cv = coord[(size_t)n * 3 + d] + c_acc[(size_t)n * 3 + d]
                                 + vel[(size_t)n * 3 + d] * vw;
                        out_c[(size_t)n * 3 + d] = cv;
                    }
                }
            }
        }
    }

    // ---- n1: K=256 on [h | m_i]
#pragma unroll
    for (int si = 0; si < 2; ++si)
#pragma unroll
        for (int ct = 0; ct < 8; ++ct) acc[si][ct] = (f32x4){0.f, 0.f, 0.f, 0.f};
#pragma unroll
    for (int kc = 0; kc < 8; ++kc)
#pragma unroll
        for (int ct = 0; ct < 8; ++ct) {
            bf16x8 b = *(const bf16x8*)(Wn1t + (size_t)(ct * 16 + l16) * 256 + kc * 32 + q * 8);
            bf16x8 a0 = (kc < 4) ? ah[0][kc & 3] : am[0][kc & 3];
            bf16x8 a1 = (kc < 4) ? ah[1][kc & 3] : am[1][kc & 3];
            acc[0][ct] = __builtin_amdgcn_mfma_f32_16x16x32_bf16(a0, b, acc[0][ct], 0, 0, 0);
            acc[1][ct] = __builtin_amdgcn_mfma_f32_16x16x32_bf16(a1, b, acc[1][ct], 0, 0, 0);
        }
    // t1 = silu(acc + bn1) -> sigma pack
#pragma unroll
    for (int si = 0; si < 2; ++si)
#pragma unroll
        for (int r = 0; r < 4; ++r) {
            int row = (wv * 2 + si) * 16 + q * 4 + r;
            float v[8];
#pragma unroll
            for (int ct = 0; ct < 8; ++ct) v[ct] = silu(acc[si][ct][r] + sBn1[ct * 16 + l16]);
            uint4 pk = make_uint4(pack2(v[0], v[1]), pack2(v[2], v[3]),
                                  pack2(v[4], v[5]), pack2(v[6], v[7]));
            *(uint4*)(sAb + row * SAB_STRIDE + l16 * 8) = pk;
        }

    BARRIER();   // t1 visible

    // ---- n2: K=128, A from sAb, B = Wn2t (sigma); out_h = acc + bn2 (fp32)
#pragma unroll
    for (int si = 0; si < 2; ++si)
#pragma unroll
        for (int ct = 0; ct < 8; ++ct) acc[si][ct] = (f32x4){0.f, 0.f, 0.f, 0.f};
    {
        bf16x8 a[2][4];
#pragma unroll
        for (int si = 0; si < 2; ++si) {
            int row = (wv * 2 + si) * 16 + l16;
#pragma unroll
            for (int kc = 0; kc < 4; ++kc)
                a[si][kc] = *(const bf16x8*)(sAb + row * SAB_STRIDE + kc * 32 + q * 8);
        }
#pragma unroll
        for (int kc = 0; kc < 4; ++kc)
#pragma unroll
            for (int ct = 0; ct < 8; ++ct) {
                bf16x8 b = *(const bf16x8*)(Wn2t + (size_t)(ct * 16 + l16) * 128 + kc * 32 + q * 8);
                acc[0][ct] = __builtin_amdgcn_mfma_f32_16x16x32_bf16(a[0][kc], b, acc[0][ct], 0, 0, 0);
                acc[1][ct] = __builtin_amdgcn_mfma_f32_16x16x32_bf16(a[1][kc], b, acc[1][ct], 0, 0, 0);
            }
    }
#pragma unroll
    for (int si = 0; si < 2; ++si)
#pragma unroll
        for (int r = 0; r < 4; ++r) {
            int row = (wv * 2 + si) * 16 + q * 4 + r;
            if (row < nval) {
                float* orow = out_h + (size_t)(n0 + row) * 128;
#pragma unroll
                for (int ct = 0; ct < 8; ++ct)
                    orow[ct * 16 + l16] = acc[si][ct][r] + sBn2[ct * 16 + l16];
            }
        }
}

extern "C" void kernel_launch(void* const* d_in, const int* in_sizes, int n_in,
                              void* d_out, int out_size, void* d_ws, size_t ws_size,
                              hipStream_t stream) {
    const float* h     = (const float*)d_in[0];
    const float* coord = (const float*)d_in[1];
    const float* vel   = (const float*)d_in[2];
    const int*   eidx  = (const int*)d_in[3];
    const float* We1 = (const float*)d_in[4];
    const float* be1 = (const float*)d_in[5];
    const float* We2 = (const float*)d_in[6];
    const float* be2 = (const float*)d_in[7];
    const float* Wc1 = (const float*)d_in[8];
    const float* bc1 = (const float*)d_in[9];
    const float* Wc2 = (const float*)d_in[10];
    const float* bc2 = (const float*)d_in[11];
    const float* Wv1 = (const float*)d_in[12];
    const float* bv1 = (const float*)d_in[13];
    const float* Wv2 = (const float*)d_in[14];
    const float* bv2 = (const float*)d_in[15];
    const float* Wn1 = (const float*)d_in[16];
    const float* bn1 = (const float*)d_in[17];
    const float* Wn2 = (const float*)d_in[18];
    const float* bn2 = (const float*)d_in[19];

    char* ws = (char*)d_ws;
    float* m_acc = (float*)ws;                                 // [NN,128] f32 = 25.6 MB
    float* c_acc = (float*)(ws + 25600000);                    // [NN,3]  f32
    unsigned short* hb   = (unsigned short*)(ws + 26200064);   // [NN,128] bf16
    unsigned short* Wt1  = (unsigned short*)(ws + 39000064);   // [128][256]
    unsigned short* Wt2  = (unsigned short*)(ws + 39065600);   // [128][128] sigma
    unsigned short* Wt3  = (unsigned short*)(ws + 39098368);   // [128][128] sigma
    unsigned short* Wv1t = (unsigned short*)(ws + 39131136);   // [128][128]
    unsigned short* Wn1t = (unsigned short*)(ws + 39163904);   // [128][256]
    unsigned short* Wn2t = (unsigned short*)(ws + 39229440);   // [128][128] sigma

    hipMemsetAsync(d_ws, 0, 26200000, stream);
    prep_h<<<6250, 256, 0, stream>>>(h, hb);
    prep_w<<<512, 256, 0, stream>>>(We1, We2, Wc1, Wv1, Wn1, Wn2,
                                    Wt1, Wt2, Wt3, Wv1t, Wn1t, Wn2t);

    egcl_edge<<<(NE + 127) / 128, BLK, 0, stream>>>(
        coord, eidx, hb, Wt1, Wt2, Wt3,
        We1, be1, be2, bc1, Wc2, bc2, m_acc, c_acc);

    float* out_h = (float*)d_out;
    float* out_c = out_h + (size_t)NN * 128;
    egcl_node<<<(NN + 127) / 128, BLK, 0, stream>>>(
        hb, coord, vel, Wv1t, bv1, Wv2, bv2, Wn1t, bn1, Wn2t, bn2,
        m_acc, c_acc, out_h, out_c);
}

// Round 6
// 459.656 us; speedup vs baseline: 1.3182x; 1.2736x over previous
//
#include <hip/hip_runtime.h>
#include <stdint.h>

#define NN 50000
#define NE 500000
#define BLK 256
#define NEB ((NE + 127) / 128)
#define SST 136   // LDS row stride in shorts (272 B -> 2-way banks on b128 reads)

#define BARRIER() asm volatile("s_waitcnt lgkmcnt(0)\n\ts_barrier" ::: "memory")

typedef __attribute__((ext_vector_type(8))) short bf16x8;
typedef __attribute__((ext_vector_type(4))) float f32x4;

__device__ __forceinline__ float silu(float x) { return x / (1.0f + __expf(-x)); }
__device__ __forceinline__ float bf2f(unsigned short s) {
    union { unsigned int u; float f; } v; v.u = ((unsigned int)s) << 16; return v.f;
}
__device__ __forceinline__ unsigned short f2bf(float f) {   // RNE
    union { float f; unsigned int u; } v; v.f = f;
    return (unsigned short)((v.u + 0x7fffu + ((v.u >> 16) & 1u)) >> 16);
}
__device__ __forceinline__ unsigned int pack2(float a, float b) {
    return (unsigned int)f2bf(a) | ((unsigned int)f2bf(b) << 16);
}
__device__ __forceinline__ bf16x8 packf8(const float* p) {
    float4 f0 = *(const float4*)p; float4 f1 = *(const float4*)(p + 4);
    union { bf16x8 v; unsigned int u[4]; } o;
    o.u[0] = pack2(f0.x, f0.y); o.u[1] = pack2(f0.z, f0.w);
    o.u[2] = pack2(f1.x, f1.y); o.u[3] = pack2(f1.z, f1.w);
    return o.v;
}

// ---------------- prep ----------------
__global__ void prep_h(const float* __restrict__ h, unsigned short* __restrict__ hb) {
    int i = blockIdx.x * 256 + threadIdx.x;
    if (i < NN * 128 / 4) {
        float4 v = ((const float4*)h)[i];
        uint2 o; o.x = pack2(v.x, v.y); o.y = pack2(v.z, v.w);
        ((uint2*)hb)[i] = o;
    }
}

// B^T layouts. sigma(col) = (col%16)*8 + col/16 ; orig_k(ks) = (ks%8)*16 + ks/8
__global__ void prep_w(const float* __restrict__ We1, const float* __restrict__ We2,
                       const float* __restrict__ Wc1, const float* __restrict__ Wv1,
                       const float* __restrict__ Wn1, const float* __restrict__ Wn2,
                       unsigned short* __restrict__ Wt1, unsigned short* __restrict__ Wt2,
                       unsigned short* __restrict__ Wt3, unsigned short* __restrict__ Wv1t,
                       unsigned short* __restrict__ Wn1t, unsigned short* __restrict__ Wn2t) {
    int i = blockIdx.x * 256 + threadIdx.x;
    if (i < 32768) {                                    // Wt1 [128][256] natural
        int j = i >> 8, k = i & 255;
        Wt1[i] = f2bf(We1[k * 128 + j]);
    } else if (i < 49152) {                             // Wt2 [128][128] sigma
        int t = i - 32768; int j = t >> 7, ks = t & 127;
        int k0 = (ks & 7) * 16 + (ks >> 3);
        Wt2[t] = f2bf(We2[k0 * 128 + j]);
    } else if (i < 65536) {                             // Wt3 [128][128] sigma
        int t = i - 49152; int j = t >> 7, ks = t & 127;
        int k0 = (ks & 7) * 16 + (ks >> 3);
        Wt3[t] = f2bf(Wc1[k0 * 128 + j]);
    } else if (i < 81920) {                             // Wv1t [128][128] natural
        int t = i - 65536; int j = t >> 7, k = t & 127;
        Wv1t[t] = f2bf(Wv1[k * 128 + j]);
    } else if (i < 114688) {                            // Wn1t [128][256]: h-half natural, m-half sigma
        int t = i - 81920; int j = t >> 8, k = t & 255;
        int ksrc;
        if (k < 128) ksrc = k;
        else { int ks = k - 128; ksrc = 128 + (ks & 7) * 16 + (ks >> 3); }
        Wn1t[t] = f2bf(Wn1[ksrc * 128 + j]);
    } else if (i < 131072) {                            // Wn2t [128][128] sigma
        int t = i - 114688; int j = t >> 7, ks = t & 127;
        int k0 = (ks & 7) * 16 + (ks >> 3);
        Wn2t[t] = f2bf(Wn2[k0 * 128 + j]);
    }
}

// ---------------- CSR build ----------------
__global__ void csr_count(const int* __restrict__ eidx, int* __restrict__ deg) {
    int e = blockIdx.x * 256 + threadIdx.x;
    if (e < NE) atomicAdd(&deg[eidx[e]], 1);
}

__global__ void scan_a(const int* __restrict__ deg, int* __restrict__ bsum) {
    __shared__ int s[256];
    int t = threadIdx.x, idx = blockIdx.x * 256 + t;
    s[t] = (idx < NN) ? deg[idx] : 0;
    __syncthreads();
    for (int off = 128; off > 0; off >>= 1) {
        if (t < off) s[t] += s[t + off];
        __syncthreads();
    }
    if (t == 0) bsum[blockIdx.x] = s[0];
}

__global__ void scan_b(int* __restrict__ bsum) {   // exclusive scan, 196 values, 1 block
    __shared__ int s[256];
    int t = threadIdx.x;
    int v = (t < 196) ? bsum[t] : 0;
    s[t] = v;
    __syncthreads();
    for (int off = 1; off < 256; off <<= 1) {
        int x = (t >= off) ? s[t - off] : 0;
        __syncthreads();
        s[t] += x;
        __syncthreads();
    }
    if (t < 196) bsum[t] = s[t] - v;
}

__global__ void scan_c(const int* __restrict__ deg, const int* __restrict__ bsum,
                       int* __restrict__ rowptr) {
    __shared__ int s[256];
    int t = threadIdx.x, idx = blockIdx.x * 256 + t;
    int v = (idx < NN) ? deg[idx] : 0;
    s[t] = v;
    __syncthreads();
    for (int off = 1; off < 256; off <<= 1) {
        int x = (t >= off) ? s[t - off] : 0;
        __syncthreads();
        s[t] += x;
        __syncthreads();
    }
    if (idx < NN) rowptr[idx] = bsum[blockIdx.x] + s[t] - v;
    if (idx == 0) rowptr[NN] = NE;
}

__global__ void csr_fill(const int* __restrict__ eidx, const int* __restrict__ rowptr,
                         int* __restrict__ cursor,
                         int* __restrict__ csr_r, int* __restrict__ csr_c) {
    int e = blockIdx.x * 256 + threadIdx.x;
    if (e < NE) {
        int r = eidx[e], c = eidx[NE + e];
        int slot = rowptr[r] + atomicAdd(&cursor[r], 1);
        csr_r[slot] = r; csr_c[slot] = c;
    }
}

// ---------------- helpers ----------------
__device__ __forceinline__ void stage256(const unsigned short* __restrict__ W, int halfk,
                                         unsigned short* sW, int tid) {
#pragma unroll
    for (int t = 0; t < 8; ++t) {
        int idx = tid + t * 256; int j = idx >> 4, g = idx & 15;
        *(uint4*)(sW + j * SST + g * 8) = *(const uint4*)(W + (size_t)j * 256 + halfk * 128 + g * 8);
    }
}
__device__ __forceinline__ void stage128(const unsigned short* __restrict__ W,
                                         unsigned short* sW, int tid) {
#pragma unroll
    for (int t = 0; t < 8; ++t) {
        int idx = tid + t * 256; int j = idx >> 4, g = idx & 15;
        *(uint4*)(sW + j * SST + g * 8) = *(const uint4*)(W + (size_t)j * 128 + g * 8);
    }
}
__device__ __forceinline__ void mfma4(const bf16x8 a[2][4], const unsigned short* sW,
                                      int l16, int q, f32x4 acc[2][8]) {
#pragma unroll
    for (int kc = 0; kc < 4; ++kc)
#pragma unroll
        for (int ct = 0; ct < 8; ++ct) {
            bf16x8 b = *(const bf16x8*)(sW + (ct * 16 + l16) * SST + kc * 32 + q * 8);
            acc[0][ct] = __builtin_amdgcn_mfma_f32_16x16x32_bf16(a[0][kc], b, acc[0][ct], 0, 0, 0);
            acc[1][ct] = __builtin_amdgcn_mfma_f32_16x16x32_bf16(a[1][kc], b, acc[1][ct], 0, 0, 0);
        }
}

// ---------------- edge kernel: CSR-ordered, segmented reduction ----------------
__global__ __launch_bounds__(BLK, 2) void egcl_edge(
    const float* __restrict__ coord,
    const int* __restrict__ csr_r, const int* __restrict__ csr_c,
    const unsigned short* __restrict__ hb,
    const unsigned short* __restrict__ Wt1,
    const unsigned short* __restrict__ Wt2,
    const unsigned short* __restrict__ Wt3,
    const float* __restrict__ We1,
    const float* __restrict__ be1, const float* __restrict__ be2,
    const float* __restrict__ bc1,
    const float* __restrict__ Wc2, const float* __restrict__ bc2,
    float* __restrict__ m_acc, float* __restrict__ c_sum)
{
    __shared__ __align__(16) unsigned short sAb[128 * SST];
    __shared__ __align__(16) unsigned short sW[128 * SST];
    __shared__ float sRad[128], sDif[128][3];
    __shared__ int sRr[128], sRc[128], sSeg[128];
    __shared__ float sBe1[128], sBe2[128], sBc1[128], sWlast[128], sWc2f[128];

    const int tid = threadIdx.x;
    const int wv = tid >> 6, lane = tid & 63, q = lane >> 4, l16 = lane & 15;
    const int e0 = blockIdx.x * 128;

    if (tid < 128) {
        sBe1[tid] = be1[tid]; sBe2[tid] = be2[tid]; sBc1[tid] = bc1[tid];
        sWlast[tid] = We1[256 * 128 + tid]; sWc2f[tid] = Wc2[tid];
        int s = e0 + tid; int sc = (s < NE) ? s : (NE - 1);
        int r = csr_r[sc], c = csr_c[sc];
        sRr[tid] = r; sRc[tid] = c;
        sSeg[tid] = (s < NE) ? r : -1;
        float dx = coord[r * 3 + 0] - coord[c * 3 + 0];
        float dy = coord[r * 3 + 1] - coord[c * 3 + 1];
        float dz = coord[r * 3 + 2] - coord[c * 3 + 2];
        float rad = fmaf(dx, dx, fmaf(dy, dy, dz * dz));
        float inv = 1.0f / (sqrtf(rad) + 1e-8f);
        sRad[tid] = rad;
        sDif[tid][0] = dx * inv; sDif[tid][1] = dy * inv; sDif[tid][2] = dz * inv;
    }
    stage256(Wt1, 0, sW, tid);
    const float bc2v = bc2[0];
    BARRIER();   // A: geometry + Wt1a visible

    f32x4 acc[2][8];
#pragma unroll
    for (int si = 0; si < 2; ++si)
#pragma unroll
        for (int ct = 0; ct < 8; ++ct) acc[si][ct] = (f32x4){0.f, 0.f, 0.f, 0.f};

    // ---- e1 half 0: A = h[r]
    {
        bf16x8 a[2][4];
#pragma unroll
        for (int si = 0; si < 2; ++si) {
            int node = sRr[(wv * 2 + si) * 16 + l16];
#pragma unroll
            for (int kc = 0; kc < 4; ++kc)
                a[si][kc] = *(const bf16x8*)(hb + (size_t)node * 128 + kc * 32 + q * 8);
        }
        mfma4(a, sW, l16, q, acc);
    }
    BARRIER();   // B: Wt1a reads done
    stage256(Wt1, 1, sW, tid);
    BARRIER();   // C: Wt1b visible
    // ---- e1 half 1: A = h[c]
    {
        bf16x8 a[2][4];
#pragma unroll
        for (int si = 0; si < 2; ++si) {
            int node = sRc[(wv * 2 + si) * 16 + l16];
#pragma unroll
            for (int kc = 0; kc < 4; ++kc)
                a[si][kc] = *(const bf16x8*)(hb + (size_t)node * 128 + kc * 32 + q * 8);
        }
        mfma4(a, sW, l16, q, acc);
    }
    BARRIER();   // D: Wt1b reads done

    // e1 epilogue: t1 = silu(acc + rad*Wlast + be1) -> sigma pack into sAb; stage Wt2
#pragma unroll
    for (int si = 0; si < 2; ++si)
#pragma unroll
        for (int r = 0; r < 4; ++r) {
            int row = (wv * 2 + si) * 16 + q * 4 + r;
            float rad = sRad[row];
            float v[8];
#pragma unroll
            for (int ct = 0; ct < 8; ++ct) {
                int col = ct * 16 + l16;
                v[ct] = silu(acc[si][ct][r] + rad * sWlast[col] + sBe1[col]);
            }
            uint4 pk = make_uint4(pack2(v[0], v[1]), pack2(v[2], v[3]),
                                  pack2(v[4], v[5]), pack2(v[6], v[7]));
            *(uint4*)(sAb + row * SST + l16 * 8) = pk;
        }
    stage128(Wt2, sW, tid);
    BARRIER();   // E: t1 + Wt2 visible

    // ---- e2: m = silu(t1 @ We2 + be2)
#pragma unroll
    for (int si = 0; si < 2; ++si)
#pragma unroll
        for (int ct = 0; ct < 8; ++ct) acc[si][ct] = (f32x4){0.f, 0.f, 0.f, 0.f};
    {
        bf16x8 a[2][4];
#pragma unroll
        for (int si = 0; si < 2; ++si) {
            int row = (wv * 2 + si) * 16 + l16;
#pragma unroll
            for (int kc = 0; kc < 4; ++kc)
                a[si][kc] = *(const bf16x8*)(sAb + row * SST + kc * 32 + q * 8);
        }
        mfma4(a, sW, l16, q, acc);
    }
    uint4 mu[2][4];
#pragma unroll
    for (int si = 0; si < 2; ++si)
#pragma unroll
        for (int r = 0; r < 4; ++r) {
            float v[8];
#pragma unroll
            for (int ct = 0; ct < 8; ++ct) v[ct] = silu(acc[si][ct][r] + sBe2[ct * 16 + l16]);
            mu[si][r] = make_uint4(pack2(v[0], v[1]), pack2(v[2], v[3]),
                                   pack2(v[4], v[5]), pack2(v[6], v[7]));
        }
    BARRIER();   // F: sAb t1-reads + Wt2 reads done
#pragma unroll
    for (int si = 0; si < 2; ++si)
#pragma unroll
        for (int r = 0; r < 4; ++r) {
            int row = (wv * 2 + si) * 16 + q * 4 + r;
            *(uint4*)(sAb + row * SST + l16 * 8) = mu[si][r];
        }
    stage128(Wt3, sW, tid);
    BARRIER();   // G: m + Wt3 visible

    // ---- c1
#pragma unroll
    for (int si = 0; si < 2; ++si)
#pragma unroll
        for (int ct = 0; ct < 8; ++ct) acc[si][ct] = (f32x4){0.f, 0.f, 0.f, 0.f};
    {
        bf16x8 a[2][4];
#pragma unroll
        for (int si = 0; si < 2; ++si) {
            int row = (wv * 2 + si) * 16 + l16;
#pragma unroll
            for (int kc = 0; kc < 4; ++kc)
                a[si][kc] = *(const bf16x8*)(sAb + row * SST + kc * 32 + q * 8);
        }
        mfma4(a, sW, l16, q, acc);
    }
    // c2: silu -> dot Wc2 -> 16-lane reduce -> c_sum atomics (1.5M total, not the wall)
#pragma unroll
    for (int si = 0; si < 2; ++si) {
        float p[4];
#pragma unroll
        for (int r = 0; r < 4; ++r) {
            float s = 0.f;
#pragma unroll
            for (int ct = 0; ct < 8; ++ct) {
                int col = ct * 16 + l16;
                float t = silu(acc[si][ct][r] + sBc1[col]);
                s = fmaf(t, sWc2f[col], s);
            }
            p[r] = s;
        }
#pragma unroll
        for (int m = 1; m < 16; m <<= 1)
#pragma unroll
            for (int r = 0; r < 4; ++r) p[r] += __shfl_xor(p[r], m, 16);
        if (l16 == 0) {
#pragma unroll
            for (int r = 0; r < 4; ++r) {
                int row = (wv * 2 + si) * 16 + q * 4 + r;
                int rn = sSeg[row];
                if (rn >= 0) {
                    float w = p[r] + bc2v;
                    atomicAdd(&c_sum[(size_t)rn * 3 + 0], sDif[row][0] * w);
                    atomicAdd(&c_sum[(size_t)rn * 3 + 1], sDif[row][1] * w);
                    atomicAdd(&c_sum[(size_t)rn * 3 + 2], sDif[row][2] * w);
                }
            }
        }
    }

    // ---- segmented m reduction: element p over rows [half*64, half*64+64)
    {
        int p = tid & 127, half = tid >> 7;
        int base = half * 64;
        float run = 0.f;
        int cur = sSeg[base];
        bool openL = true;   // current run touches segment start (may continue left)
#pragma unroll 1
        for (int i = 0; i < 64; ++i) {
            int row = base + i;
            int rr = sSeg[row];
            if (rr != cur) {
                if (cur >= 0) {
                    float* dst = &m_acc[(size_t)cur * 128 + p];
                    if (openL) atomicAdd(dst, run);
                    else       *dst = run;   // block-interior run: exclusive writer
                }
                run = 0.f; cur = rr; openL = false;
            }
            run += bf2f(sAb[row * SST + p]);
        }
        if (cur >= 0) atomicAdd(&m_acc[(size_t)cur * 128 + p], run);  // open at right
    }
}

// ---------------- node kernel: MFMA vel-MLP + node-MLP ----------------
__global__ __launch_bounds__(BLK, 3) void egcl_node(
    const unsigned short* __restrict__ hb,
    const float* __restrict__ coord,
    const float* __restrict__ vel,
    const unsigned short* __restrict__ Wv1t, const float* __restrict__ bv1,
    const float* __restrict__ Wv2, const float* __restrict__ bv2,
    const unsigned short* __restrict__ Wn1t, const float* __restrict__ bn1,
    const unsigned short* __restrict__ Wn2t, const float* __restrict__ bn2,
    const float* __restrict__ m_acc, const float* __restrict__ c_sum,
    float* __restrict__ out_h, float* __restrict__ out_c)
{
    __shared__ __align__(16) unsigned short sAb[128 * SST];
    __shared__ float sBv1[128], sWv2f[128], sBn1[128], sBn2[128];

    const int tid = threadIdx.x;
    const int wv = tid >> 6, lane = tid & 63, q = lane >> 4, l16 = lane & 15;
    const int n0 = blockIdx.x * 128;
    int nval = NN - n0; if (nval > 128) nval = 128;

    if (tid < 128) {
        sBv1[tid] = bv1[tid]; sWv2f[tid] = Wv2[tid];
        sBn1[tid] = bn1[tid]; sBn2[tid] = bn2[tid];
    }
    const float bv2v = bv2[0];

    bf16x8 ah[2][4], am[2][4];   // am reads sigma-packed m_acc; Wn1t m-half is sigma'd
#pragma unroll
    for (int si = 0; si < 2; ++si) {
        int row = (wv * 2 + si) * 16 + l16;
        int nn = n0 + row; if (nn >= NN) nn = NN - 1;
#pragma unroll
        for (int kc = 0; kc < 4; ++kc) {
            ah[si][kc] = *(const bf16x8*)(hb + (size_t)nn * 128 + kc * 32 + q * 8);
            am[si][kc] = packf8(m_acc + (size_t)nn * 128 + kc * 32 + q * 8);
        }
    }

    BARRIER();   // biases visible

    f32x4 acc[2][8];
    // ---- vel MLP
#pragma unroll
    for (int si = 0; si < 2; ++si)
#pragma unroll
        for (int ct = 0; ct < 8; ++ct) acc[si][ct] = (f32x4){0.f, 0.f, 0.f, 0.f};
#pragma unroll
    for (int kc = 0; kc < 4; ++kc)
#pragma unroll
        for (int ct = 0; ct < 8; ++ct) {
            bf16x8 b = *(const bf16x8*)(Wv1t + (size_t)(ct * 16 + l16) * 128 + kc * 32 + q * 8);
            acc[0][ct] = __builtin_amdgcn_mfma_f32_16x16x32_bf16(ah[0][kc], b, acc[0][ct], 0, 0, 0);
            acc[1][ct] = __builtin_amdgcn_mfma_f32_16x16x32_bf16(ah[1][kc], b, acc[1][ct], 0, 0, 0);
        }
#pragma unroll
    for (int si = 0; si < 2; ++si) {
        float p[4];
#pragma unroll
        for (int r = 0; r < 4; ++r) {
            float s = 0.f;
#pragma unroll
            for (int ct = 0; ct < 8; ++ct) {
                int col = ct * 16 + l16;
                float t = silu(acc[si][ct][r] + sBv1[col]);
                s = fmaf(t, sWv2f[col], s);
            }
            p[r] = s;
        }
#pragma unroll
        for (int m = 1; m < 16; m <<= 1)
#pragma unroll
            for (int r = 0; r < 4; ++r) p[r] += __shfl_xor(p[r], m, 16);
        if (l16 == 0) {
#pragma unroll
            for (int r = 0; r < 4; ++r) {
                int row = (wv * 2 + si) * 16 + q * 4 + r;
                int n = n0 + row;
                if (row < nval) {
                    float vw = p[r] + bv2v;
#pragma unroll
                    for (int d = 0; d < 3; ++d) {
                        float cv = coord[(size_t)n * 3 + d] + c_sum[(size_t)n * 3 + d]
                                 + vel[(size_t)n * 3 + d] * vw;
                        out_c[(size_t)n * 3 + d] = cv;
                    }
                }
            }
        }
    }

    // ---- n1: K=256 on [h | m_i]
#pragma unroll
    for (int si = 0; si < 2; ++si)
#pragma unroll
        for (int ct = 0; ct < 8; ++ct) acc[si][ct] = (f32x4){0.f, 0.f, 0.f, 0.f};
#pragma unroll
    for (int kc = 0; kc < 8; ++kc)
#pragma unroll
        for (int ct = 0; ct < 8; ++ct) {
            bf16x8 b = *(const bf16x8*)(Wn1t + (size_t)(ct * 16 + l16) * 256 + kc * 32 + q * 8);
            bf16x8 a0 = (kc < 4) ? ah[0][kc & 3] : am[0][kc & 3];
            bf16x8 a1 = (kc < 4) ? ah[1][kc & 3] : am[1][kc & 3];
            acc[0][ct] = __builtin_amdgcn_mfma_f32_16x16x32_bf16(a0, b, acc[0][ct], 0, 0, 0);
            acc[1][ct] = __builtin_amdgcn_mfma_f32_16x16x32_bf16(a1, b, acc[1][ct], 0, 0, 0);
        }
#pragma unroll
    for (int si = 0; si < 2; ++si)
#pragma unroll
        for (int r = 0; r < 4; ++r) {
            int row = (wv * 2 + si) * 16 + q * 4 + r;
            float v[8];
#pragma unroll
            for (int ct = 0; ct < 8; ++ct) v[ct] = silu(acc[si][ct][r] + sBn1[ct * 16 + l16]);
            uint4 pk = make_uint4(pack2(v[0], v[1]), pack2(v[2], v[3]),
                                  pack2(v[4], v[5]), pack2(v[6], v[7]));
            *(uint4*)(sAb + row * SST + l16 * 8) = pk;
        }

    BARRIER();   // t1 visible

    // ---- n2
#pragma unroll
    for (int si = 0; si < 2; ++si)
#pragma unroll
        for (int ct = 0; ct < 8; ++ct) acc[si][ct] = (f32x4){0.f, 0.f, 0.f, 0.f};
    {
        bf16x8 a[2][4];
#pragma unroll
        for (int si = 0; si < 2; ++si) {
            int row = (wv * 2 + si) * 16 + l16;
#pragma unroll
            for (int kc = 0; kc < 4; ++kc)
                a[si][kc] = *(const bf16x8*)(sAb + row * SST + kc * 32 + q * 8);
        }
#pragma unroll
        for (int kc = 0; kc < 4; ++kc)
#pragma unroll
            for (int ct = 0; ct < 8; ++ct) {
                bf16x8 b = *(const bf16x8*)(Wn2t + (size_t)(ct * 16 + l16) * 128 + kc * 32 + q * 8);
                acc[0][ct] = __builtin_amdgcn_mfma_f32_16x16x32_bf16(a[0][kc], b, acc[0][ct], 0, 0, 0);
                acc[1][ct] = __builtin_amdgcn_mfma_f32_16x16x32_bf16(a[1][kc], b, acc[1][ct], 0, 0, 0);
            }
    }
#pragma unroll
    for (int si = 0; si < 2; ++si)
#pragma unroll
        for (int r = 0; r < 4; ++r) {
            int row = (wv * 2 + si) * 16 + q * 4 + r;
            if (row < nval) {
                float* orow = out_h + (size_t)(n0 + row) * 128;
#pragma unroll
                for (int ct = 0; ct < 8; ++ct)
                    orow[ct * 16 + l16] = acc[si][ct][r] + sBn2[ct * 16 + l16];
            }
        }
}

extern "C" void kernel_launch(void* const* d_in, const int* in_sizes, int n_in,
                              void* d_out, int out_size, void* d_ws, size_t ws_size,
                              hipStream_t stream) {
    const float* h     = (const float*)d_in[0];
    const float* coord = (const float*)d_in[1];
    const float* vel   = (const float*)d_in[2];
    const int*   eidx  = (const int*)d_in[3];
    const float* We1 = (const float*)d_in[4];
    const float* be1 = (const float*)d_in[5];
    const float* We2 = (const float*)d_in[6];
    const float* be2 = (const float*)d_in[7];
    const float* Wc1 = (const float*)d_in[8];
    const float* bc1 = (const float*)d_in[9];
    const float* Wc2 = (const float*)d_in[10];
    const float* bc2 = (const float*)d_in[11];
    const float* Wv1 = (const float*)d_in[12];
    const float* bv1 = (const float*)d_in[13];
    const float* Wv2 = (const float*)d_in[14];
    const float* bv2 = (const float*)d_in[15];
    const float* Wn1 = (const float*)d_in[16];
    const float* bn1 = (const float*)d_in[17];
    const float* Wn2 = (const float*)d_in[18];
    const float* bn2 = (const float*)d_in[19];

    char* ws = (char*)d_ws;
    float* m_acc = (float*)ws;                                  // [NN][128] f32 sigma-packed
    float* c_sum = (float*)(ws + 25600000);                     // [NN][3] f32
    unsigned short* hb   = (unsigned short*)(ws + 26200064);    // [NN][128] bf16
    unsigned short* Wt1  = (unsigned short*)(ws + 39000064);
    unsigned short* Wt2  = (unsigned short*)(ws + 39065600);
    unsigned short* Wt3  = (unsigned short*)(ws + 39098368);
    unsigned short* Wv1t = (unsigned short*)(ws + 39131136);
    unsigned short* Wn1t = (unsigned short*)(ws + 39163904);
    unsigned short* Wn2t = (unsigned short*)(ws + 39229440);
    int* deg    = (int*)(ws + 39262208);                        // [NN]
    int* cursor = (int*)(ws + 39462208);                        // [NN]
    int* rowptr = (int*)(ws + 39662208);                        // [NN+1]
    int* bsum   = (int*)(ws + 39862272);                        // [256]
    int* csr_r  = (int*)(ws + 39863296);                        // [NE]
    int* csr_c  = (int*)(ws + 41863296);                        // [NE]

    hipMemsetAsync(ws, 0, 26200000, stream);          // m_acc + c_sum
    hipMemsetAsync(ws + 39262208, 0, 400000, stream); // deg + cursor

    prep_h<<<6250, 256, 0, stream>>>(h, hb);
    prep_w<<<512, 256, 0, stream>>>(We1, We2, Wc1, Wv1, Wn1, Wn2,
                                    Wt1, Wt2, Wt3, Wv1t, Wn1t, Wn2t);

    csr_count<<<1954, 256, 0, stream>>>(eidx, deg);
    scan_a<<<196, 256, 0, stream>>>(deg, bsum);
    scan_b<<<1, 256, 0, stream>>>(bsum);
    scan_c<<<196, 256, 0, stream>>>(deg, bsum, rowptr);
    csr_fill<<<1954, 256, 0, stream>>>(eidx, rowptr, cursor, csr_r, csr_c);

    egcl_edge<<<NEB, BLK, 0, stream>>>(
        coord, csr_r, csr_c, hb, Wt1, Wt2, Wt3,
        We1, be1, be2, bc1, Wc2, bc2, m_acc, c_sum);

    float* out_h = (float*)d_out;
    float* out_c = out_h + (size_t)NN * 128;
    egcl_node<<<(NN + 127) / 128, BLK, 0, stream>>>(
        hb, coord, vel, Wv1t, bv1, Wv2, bv2, Wn1t, bn1, Wn2t, bn2,
        m_acc, c_sum, out_h, out_c);
}